// Round 7
// baseline (1231.627 us; speedup 1.0000x reference)
//
#include <hip/hip_runtime.h>

// GCN: 100K nodes, 3.2M edges, 128 -> 16 -> 16 -> 16 -> 2, mean-pool to 64 graphs.
// R17 vs R16: k_bsort DELETED. Aggregation is order-independent, so the per-bucket
// counting sort (~35us) existed only to enable per-node row loops. Now the agg
// kernels are bucket-wise: block b consumes bucket b's unsorted pkt list
// ((dstLocal<<17)|src from k_build), one edge per thread-iteration, accumulating
// into LDS acc[256][17] via ds_add_f32 (stride-17 pad -> banks spread; ~2 lanes/
// bank is free). Epilogue: thread t owns node t: +self, bias, PReLU, 16x16
// transform, coalesced 32B write. Also kills row-length imbalance (threads share
// edges, not rows). k_dinv (new, ~5us) computes degrees/dinv per bucket.
// Agg inner-loop micro-opts are DEAD ENDS (R11/R14/R15/R16 all neutral: gather
// is ~1 line-request/edge, MSHR-floor ~20us/pass). Build: R11 k_build unchanged.
// absmax canary moves with summation order (~1e-4 scale expected).

#define NN 100000
#define NE 3200000
#define NF 128
#define NH 16
#define NO 2
#define NG 64
#define NBLK 391        // ceil(NN/256)
#define BN 256          // nodes per bucket
#define NBUK 391        // ceil(NN/BN)
#define CHUNK 4096
#define NBLKA 782       // ceil(NE/CHUNK)
#define CAPF 10240      // bucket region capacity (mean 8184, sigma ~90)
#define NT0 6250        // 16-node tiles

typedef __attribute__((ext_vector_type(8))) short short8;
typedef __attribute__((ext_vector_type(4))) float float4v;

// ---------------- dtype-dispatched IO helpers ----------------

__device__ __forceinline__ float ldf(const void* p, int i, int f32) {
  if (f32) return ((const float*)p)[i];
  unsigned int u = ((const unsigned short*)p)[i];
  return __uint_as_float(u << 16);
}
__device__ __forceinline__ int ldi(const void* p, int i, int i64) {
  if (i64) return (int)((const long long*)p)[i];
  return ((const int*)p)[i];
}
__device__ __forceinline__ void stf(void* p, int i, float v, int f32) {
  if (f32) {
    ((float*)p)[i] = v;
  } else {
    unsigned int w = __float_as_uint(v);
    unsigned int r = (w + 0x7fffu + ((w >> 16) & 1u)) >> 16;
    ((unsigned short*)p)[i] = (unsigned short)r;
  }
}
__device__ __forceinline__ float bf16lo(unsigned int u) { return __uint_as_float(u << 16); }
__device__ __forceinline__ float bf16hi(unsigned int u) { return __uint_as_float(u & 0xffff0000u); }
__device__ __forceinline__ unsigned int packbf(float x, float y) {
  unsigned int a = __float_as_uint(x);
  a = (a + 0x7fffu + ((a >> 16) & 1u)) >> 16;
  unsigned int b = __float_as_uint(y);
  b = (b + 0x7fffu + ((b >> 16) & 1u)) & 0xffff0000u;
  return a | b;
}
__device__ __forceinline__ short bf16rne(float v) {
  unsigned int w = __float_as_uint(v);
  return (short)((w + 0x7fffu + ((w >> 16) & 1u)) >> 16);
}
__device__ __forceinline__ int okf(float v) { return (v == v) && (fabsf(v) < 1e30f); }
__device__ __forceinline__ void nflag(int* diag, int bad, int bit) {
  if (__any(bad)) {
    if ((threadIdx.x & 63) == 0) atomicOr(diag + 2, 1 << bit);
  }
}
__device__ __forceinline__ int clampi(int v, int hi) {
  return (unsigned)v < (unsigned)hi ? v : 0;
}

// ---------------- dtype sniff + workspace-control zeroing ----------------

// zbase = first 2496 B of ws: diag(16 ints) | pool(192 fl) | cursor(391+ ints)
__global__ __launch_bounds__(1024) void k_sniff(const void* x, const void* ei, int* zbase) {
  int tid = threadIdx.x;
  if (tid < 624) zbase[tid] = 0;
  __syncthreads();
  if (tid < 64) {
    unsigned int xv = ((const unsigned int*)x)[tid];
    unsigned int e = (xv >> 7) & 0xffu;
    int hit = (e >= 116u && e <= 133u);
    int hits = __popcll(__ballot(hit));
    unsigned int ev = ((const unsigned int*)ei)[2 * tid + 1];
    int nzc = __popcll(__ballot(ev != 0u));
    if (tid == 0) {
      zbase[0] = (hits < 32) ? 1 : 0;  // floats are fp32
      zbase[1] = (nzc == 0) ? 1 : 0;   // ints are int64
    }
  }
}

// ---------------- build: bucketed scatter, one LDS-atomic pass, 512 threads ----------------

__global__ __launch_bounds__(512) void k_build(const void* ei, const int* __restrict__ diag,
                                               int* __restrict__ cursor, int* __restrict__ ents) {
  __shared__ int spktA[CHUNK];             // 16K  (dst&255)<<17|src
  __shared__ unsigned short sbid[CHUNK];   // 8K   bucket id
  __shared__ unsigned short srank[CHUNK];  // 8K   rank within bucket
  __shared__ int spktB[CHUNK];             // 16K  reordered pkt
  __shared__ int gpos[CHUNK];              // 16K  global dest
  __shared__ int lscan[512];               // 2K   counts -> inclusive scan
  __shared__ int sexcl[NBUK];              // 1.6K
  __shared__ int goff[NBUK];               // 1.6K
  int tid = threadIdx.x, blk = blockIdx.x;
  lscan[tid] = 0;
  __syncthreads();
  int i64 = diag[1];
  int base = blk * CHUNK;
  int n = NE - base; n = n > CHUNK ? CHUNK : n;
  for (int i = tid; i < n; i += 512) {
    int sv = clampi(ldi(ei, base + i, i64), NN);
    int dv = clampi(ldi(ei, NE + base + i, i64), NN);
    int b = dv >> 8;
    spktA[i] = ((dv & 255) << 17) | sv;
    sbid[i] = (unsigned short)b;
    srank[i] = (unsigned short)atomicAdd(&lscan[b], 1);
  }
  __syncthreads();
  // inclusive scan of lscan[0..511], 512 threads
  for (int off = 1; off < 512; off <<= 1) {
    int v = (tid >= off) ? lscan[tid - off] : 0;
    __syncthreads();
    lscan[tid] += v;
    __syncthreads();
  }
  if (tid < NBUK) {
    int b = tid;
    int incl = lscan[b];
    int excl = (b > 0) ? lscan[b - 1] : 0;
    int cnt = incl - excl;
    sexcl[b] = excl;
    int rbase = cnt ? atomicAdd(&cursor[b], cnt) : 0;
    goff[b] = b * CAPF + rbase - excl;
  }
  __syncthreads();
  for (int i = tid; i < n; i += 512) {
    int b = sbid[i];
    int rr = sexcl[b] + srank[i];
    spktB[rr] = spktA[i];
    int gp = goff[b] + rr;
    int hi = b * CAPF + CAPF - 1;
    gpos[rr] = gp <= hi ? gp : hi;  // overflow clamp (flagged in k_dinv)
  }
  __syncthreads();
  for (int r = tid; r < n; r += 512) ents[gpos[r]] = spktB[r];
}

// ---------------- degrees -> dinv (per bucket, replaces k_bsort) ----------------

__global__ __launch_bounds__(256) void k_dinv(const int* __restrict__ ents,
                                              const int* __restrict__ cursor,
                                              float* __restrict__ dinv, int* __restrict__ diag) {
  __shared__ int cnt[BN];
  int tid = threadIdx.x, b = blockIdx.x;
  int bs = b * CAPF;
  int n = cursor[b];
  if (n > CAPF) { n = CAPF; if (tid == 0) atomicOr(diag + 2, 1 << 9); }
  cnt[tid] = 0;
  __syncthreads();
  for (int i = tid; i < n; i += 256) atomicAdd(&cnt[ents[bs + i] >> 17], 1);
  __syncthreads();
  int node = (b << 8) + tid;
  if (node < NN) dinv[node] = rsqrtf((float)(cnt[tid] + 1));
}

// ---------------- input transform: hs0 = dinv * (x @ W0), bf16-packed ----------------
// Unified MFMA path; fp32 inputs vector-loaded and RNE-rounded to bf16 in-register.

__global__ __launch_bounds__(256) void k_t0(const void* __restrict__ x, const void* __restrict__ W0,
                                            const float* __restrict__ dinv,
                                            int* __restrict__ diag, unsigned int* __restrict__ out) {
  int tid = threadIdx.x;
  int f32 = diag[0];
  int wave = tid >> 6, lane = tid & 63;
  int nfe = lane & 15, quad = lane >> 4;
  short8 bfr[4];
  if (f32) {
    const float* wf = (const float*)W0;
#pragma unroll
    for (int mf = 0; mf < 4; ++mf) {
      short8 t;
#pragma unroll
      for (int j = 0; j < 8; ++j) t[j] = bf16rne(wf[(mf * 32 + quad * 8 + j) * NH + nfe]);
      bfr[mf] = t;
    }
  } else {
    const unsigned short* wu = (const unsigned short*)W0;
#pragma unroll
    for (int mf = 0; mf < 4; ++mf) {
      short8 t;
#pragma unroll
      for (int j = 0; j < 8; ++j) t[j] = (short)wu[(mf * 32 + quad * 8 + j) * NH + nfe];
      bfr[mf] = t;
    }
  }
  int tile = blockIdx.x * 4 + wave;
  if (tile >= NT0) return;
  int node0 = tile * 16;
  float4v c = {0.f, 0.f, 0.f, 0.f};
  if (f32) {
    const float4v* xrow = (const float4v*)((const float*)x + (node0 + nfe) * NF);
#pragma unroll
    for (int mf = 0; mf < 4; ++mf) {
      float4v f0 = xrow[mf * 8 + quad * 2];
      float4v f1 = xrow[mf * 8 + quad * 2 + 1];
      short8 a;
#pragma unroll
      for (int j = 0; j < 4; ++j) {
        a[j] = bf16rne(f0[j]);
        a[j + 4] = bf16rne(f1[j]);
      }
      c = __builtin_amdgcn_mfma_f32_16x16x32_bf16(a, bfr[mf], c, 0, 0, 0);
    }
  } else {
    const short8* xrow = (const short8*)((const unsigned short*)x + (node0 + nfe) * NF);
#pragma unroll
    for (int mf = 0; mf < 4; ++mf) {
      c = __builtin_amdgcn_mfma_f32_16x16x32_bf16(xrow[mf * 4 + quad], bfr[mf], c, 0, 0, 0);
    }
  }
  int bad = 0;
#pragma unroll
  for (int r = 0; r < 4; ++r) {
    int node = node0 + quad * 4 + r;
    float v = c[r] * dinv[node];
    float o = __shfl_xor(v, 1);
    if (!(nfe & 1)) out[node * 8 + (nfe >> 1)] = packbf(v, o);
    bad |= !okf(v);
  }
  nflag(diag, bad, 0);
}

// ---------------- bucket-wise fused aggregate + PReLU + transform ----------------

// Block b owns bucket b (256 nodes, ~8200 edges, unsorted pkt list).
// Edge phase: thread handles one edge/iter: gather 32B of hs[src], 16 LDS f32
// atomics into acc[dstLocal][.] (stride 17 pad). Epilogue: thread t = node t.
__global__ __launch_bounds__(256) void k_aggB(const uint4* __restrict__ hin,
                                              const int* __restrict__ ents,
                                              const int* __restrict__ cursor,
                                              const float* __restrict__ dinv,
                                              const void* __restrict__ b, const void* __restrict__ a,
                                              const void* __restrict__ Wn,
                                              int* __restrict__ diag, int bit,
                                              uint4* __restrict__ hout) {
  __shared__ float acc[BN * 17];   // 17.4K, stride-17 pad
  __shared__ float ws[NH * NH];    // 1K
  int tid = threadIdx.x, bk = blockIdx.x;
  int f32 = diag[0];
  ws[tid] = ldf(Wn, tid, f32);
#pragma unroll
  for (int i = 0; i < 17; ++i) acc[tid + 256 * i] = 0.f;
  __syncthreads();
  int bs = bk * CAPF;
  int n = cursor[bk];
  n = n > CAPF ? CAPF : n;
  for (int i = tid; i < n; i += 256) {
    int pkt = ents[bs + i];
    int src = pkt & 0x1FFFF;
    int dl = pkt >> 17;
    uint4 h0 = hin[src * 2];
    uint4 h1 = hin[src * 2 + 1];
    float* A = &acc[dl * 17];
    atomicAdd(&A[0], bf16lo(h0.x));
    atomicAdd(&A[1], bf16hi(h0.x));
    atomicAdd(&A[2], bf16lo(h0.y));
    atomicAdd(&A[3], bf16hi(h0.y));
    atomicAdd(&A[4], bf16lo(h0.z));
    atomicAdd(&A[5], bf16hi(h0.z));
    atomicAdd(&A[6], bf16lo(h0.w));
    atomicAdd(&A[7], bf16hi(h0.w));
    atomicAdd(&A[8], bf16lo(h1.x));
    atomicAdd(&A[9], bf16hi(h1.x));
    atomicAdd(&A[10], bf16lo(h1.y));
    atomicAdd(&A[11], bf16hi(h1.y));
    atomicAdd(&A[12], bf16lo(h1.z));
    atomicAdd(&A[13], bf16hi(h1.z));
    atomicAdd(&A[14], bf16lo(h1.w));
    atomicAdd(&A[15], bf16hi(h1.w));
  }
  __syncthreads();
  int node = (bk << 8) + tid;
  if (node >= NN) return;
  uint4 s0 = hin[node * 2];
  uint4 s1 = hin[node * 2 + 1];
  float f[16];
  f[0] = acc[tid * 17 + 0] + bf16lo(s0.x);
  f[1] = acc[tid * 17 + 1] + bf16hi(s0.x);
  f[2] = acc[tid * 17 + 2] + bf16lo(s0.y);
  f[3] = acc[tid * 17 + 3] + bf16hi(s0.y);
  f[4] = acc[tid * 17 + 4] + bf16lo(s0.z);
  f[5] = acc[tid * 17 + 5] + bf16hi(s0.z);
  f[6] = acc[tid * 17 + 6] + bf16lo(s0.w);
  f[7] = acc[tid * 17 + 7] + bf16hi(s0.w);
  f[8] = acc[tid * 17 + 8] + bf16lo(s1.x);
  f[9] = acc[tid * 17 + 9] + bf16hi(s1.x);
  f[10] = acc[tid * 17 + 10] + bf16lo(s1.y);
  f[11] = acc[tid * 17 + 11] + bf16hi(s1.y);
  f[12] = acc[tid * 17 + 12] + bf16lo(s1.z);
  f[13] = acc[tid * 17 + 13] + bf16hi(s1.z);
  f[14] = acc[tid * 17 + 14] + bf16lo(s1.w);
  f[15] = acc[tid * 17 + 15] + bf16hi(s1.w);
  float dv = dinv[node];
  float av = ldf(a, 0, f32);
  float pp[16];
#pragma unroll
  for (int j = 0; j < 16; ++j) {
    float u = dv * f[j] + ldf(b, j, f32);
    pp[j] = u > 0.f ? u : av * u;
  }
  float t[16];
#pragma unroll
  for (int i = 0; i < 16; ++i) t[i] = 0.f;
#pragma unroll
  for (int j = 0; j < 16; ++j) {
#pragma unroll
    for (int i = 0; i < 16; ++i) t[i] += pp[j] * ws[j * NH + i];
  }
  uint4 o0, o1;
  o0.x = packbf(dv * t[0], dv * t[1]);
  o0.y = packbf(dv * t[2], dv * t[3]);
  o0.z = packbf(dv * t[4], dv * t[5]);
  o0.w = packbf(dv * t[6], dv * t[7]);
  o1.x = packbf(dv * t[8], dv * t[9]);
  o1.y = packbf(dv * t[10], dv * t[11]);
  o1.z = packbf(dv * t[12], dv * t[13]);
  o1.w = packbf(dv * t[14], dv * t[15]);
  hout[node * 2] = o0;
  hout[node * 2 + 1] = o1;
  nflag(diag, !okf(t[0]) || !okf(t[15]), bit);
}

// Last hidden layer: bucket-wise aggregate + PReLU + W3 (16->2), float2 out.
__global__ __launch_bounds__(256) void k_aggB3(const uint4* __restrict__ hin,
                                               const int* __restrict__ ents,
                                               const int* __restrict__ cursor,
                                               const float* __restrict__ dinv,
                                               const void* __restrict__ b, const void* __restrict__ a,
                                               const void* __restrict__ W3,
                                               int* __restrict__ diag, float2* __restrict__ hout) {
  __shared__ float acc[BN * 17];
  __shared__ float ws[NH * NO];
  int tid = threadIdx.x, bk = blockIdx.x;
  int f32 = diag[0];
  if (tid < NH * NO) ws[tid] = ldf(W3, tid, f32);
#pragma unroll
  for (int i = 0; i < 17; ++i) acc[tid + 256 * i] = 0.f;
  __syncthreads();
  int bs = bk * CAPF;
  int n = cursor[bk];
  n = n > CAPF ? CAPF : n;
  for (int i = tid; i < n; i += 256) {
    int pkt = ents[bs + i];
    int src = pkt & 0x1FFFF;
    int dl = pkt >> 17;
    uint4 h0 = hin[src * 2];
    uint4 h1 = hin[src * 2 + 1];
    float* A = &acc[dl * 17];
    atomicAdd(&A[0], bf16lo(h0.x));
    atomicAdd(&A[1], bf16hi(h0.x));
    atomicAdd(&A[2], bf16lo(h0.y));
    atomicAdd(&A[3], bf16hi(h0.y));
    atomicAdd(&A[4], bf16lo(h0.z));
    atomicAdd(&A[5], bf16hi(h0.z));
    atomicAdd(&A[6], bf16lo(h0.w));
    atomicAdd(&A[7], bf16hi(h0.w));
    atomicAdd(&A[8], bf16lo(h1.x));
    atomicAdd(&A[9], bf16hi(h1.x));
    atomicAdd(&A[10], bf16lo(h1.y));
    atomicAdd(&A[11], bf16hi(h1.y));
    atomicAdd(&A[12], bf16lo(h1.z));
    atomicAdd(&A[13], bf16hi(h1.z));
    atomicAdd(&A[14], bf16lo(h1.w));
    atomicAdd(&A[15], bf16hi(h1.w));
  }
  __syncthreads();
  int node = (bk << 8) + tid;
  if (node >= NN) return;
  uint4 s0 = hin[node * 2];
  uint4 s1 = hin[node * 2 + 1];
  float f[16];
  f[0] = acc[tid * 17 + 0] + bf16lo(s0.x);
  f[1] = acc[tid * 17 + 1] + bf16hi(s0.x);
  f[2] = acc[tid * 17 + 2] + bf16lo(s0.y);
  f[3] = acc[tid * 17 + 3] + bf16hi(s0.y);
  f[4] = acc[tid * 17 + 4] + bf16lo(s0.z);
  f[5] = acc[tid * 17 + 5] + bf16hi(s0.z);
  f[6] = acc[tid * 17 + 6] + bf16lo(s0.w);
  f[7] = acc[tid * 17 + 7] + bf16hi(s0.w);
  f[8] = acc[tid * 17 + 8] + bf16lo(s1.x);
  f[9] = acc[tid * 17 + 9] + bf16hi(s1.x);
  f[10] = acc[tid * 17 + 10] + bf16lo(s1.y);
  f[11] = acc[tid * 17 + 11] + bf16hi(s1.y);
  f[12] = acc[tid * 17 + 12] + bf16lo(s1.z);
  f[13] = acc[tid * 17 + 13] + bf16hi(s1.z);
  f[14] = acc[tid * 17 + 14] + bf16lo(s1.w);
  f[15] = acc[tid * 17 + 15] + bf16hi(s1.w);
  float dv = dinv[node];
  float av = ldf(a, 0, f32);
  float u0 = 0.f, u1 = 0.f;
#pragma unroll
  for (int j = 0; j < 16; ++j) {
    float u = dv * f[j] + ldf(b, j, f32);
    u = u > 0.f ? u : av * u;
    u0 += u * ws[j * NO];
    u1 += u * ws[j * NO + 1];
  }
  hout[node] = make_float2(dv * u0, dv * u1);
  nflag(diag, !okf(u0) || !okf(u1), 6);
}

// Final bucket-wise 2-wide aggregation + b3 + fused mean-pool accumulation.
__global__ __launch_bounds__(256) void k_aggB2p(const float2* __restrict__ tin,
                                                const int* __restrict__ ents,
                                                const int* __restrict__ cursor,
                                                const float* __restrict__ dinv,
                                                const void* __restrict__ b3,
                                                const void* __restrict__ batch,
                                                int* __restrict__ diag, float* __restrict__ pool) {
  __shared__ float acc[BN * 3];    // stride-3 pad
  __shared__ float ssum[NG * NO];
  __shared__ float scnt[NG];
  int tid = threadIdx.x, bk = blockIdx.x;
  int f32 = diag[0], i64 = diag[1];
  acc[tid] = 0.f;
  acc[tid + 256] = 0.f;
  acc[tid + 512] = 0.f;
  if (tid < NG * NO) ssum[tid] = 0.f;
  if (tid < NG) scnt[tid] = 0.f;
  __syncthreads();
  int bs = bk * CAPF;
  int n = cursor[bk];
  n = n > CAPF ? CAPF : n;
  for (int i = tid; i < n; i += 256) {
    int pkt = ents[bs + i];
    int src = pkt & 0x1FFFF;
    int dl = pkt >> 17;
    float2 tv = tin[src];
    atomicAdd(&acc[dl * 3], tv.x);
    atomicAdd(&acc[dl * 3 + 1], tv.y);
  }
  __syncthreads();
  int node = (bk << 8) + tid;
  if (node < NN) {
    float2 t = tin[node];
    float a0 = acc[tid * 3] + t.x;
    float a1 = acc[tid * 3 + 1] + t.y;
    float dv = dinv[node];
    a0 = dv * a0 + ldf(b3, 0, f32);
    a1 = dv * a1 + ldf(b3, 1, f32);
    int g = ldi(batch, node, i64);
    g = (unsigned)g < NG ? g : 0;
    atomicAdd(&ssum[g * 2], a0);
    atomicAdd(&ssum[g * 2 + 1], a1);
    atomicAdd(&scnt[g], 1.f);
    nflag(diag, !okf(a0) || !okf(a1), 7);
  }
  __syncthreads();
  if (tid < NG * NO && ssum[tid] != 0.f) atomicAdd(&pool[tid], ssum[tid]);
  if (tid < NG && scnt[tid] != 0.f) atomicAdd(&pool[NG * NO + tid], scnt[tid]);
}

__global__ __launch_bounds__(128) void k_final(const float* __restrict__ pool,
                                               const int* __restrict__ diag, void* __restrict__ out) {
  int i = threadIdx.x;
  int f32 = diag[0], i64 = diag[1], stg = diag[2];
  float c = pool[NG * NO + (i >> 1)];
  c = c > 1.f ? c : 1.f;
  float v = pool[i] / c;
  if (stg != 0 || !okf(v)) {
    int stage = stg ? __ffs(stg) : 15;
    v = 1024.0f + stage * 64.0f + f32 * 16.0f + i64 * 8.0f;
  }
  stf(out, i, v, f32);
}

__global__ __launch_bounds__(128) void k_diag_ws(void* out, float v) {
  unsigned int w = __float_as_uint(v);
  ((unsigned short*)out)[threadIdx.x] = (unsigned short)(w >> 16);
}

// ---------------- launch ----------------

extern "C" void kernel_launch(void* const* d_in, const int* in_sizes, int n_in,
                              void* d_out, int out_size, void* d_ws, size_t ws_size,
                              hipStream_t stream) {
  const void* x  = d_in[0];
  const void* ei = d_in[1];
  const void* batch = d_in[2];
  const void* W0 = d_in[3];
  const void* b0 = d_in[4];
  const void* a0 = d_in[5];
  const void* W1 = d_in[6];
  const void* b1 = d_in[7];
  const void* a1 = d_in[8];
  const void* W2 = d_in[9];
  const void* b2 = d_in[10];
  const void* a2 = d_in[11];
  const void* W3 = d_in[12];
  const void* b3 = d_in[13];

  // workspace layout (bytes)
  char* w = (char*)d_ws;
  int* diag         = (int*)(w + 0);            // 64
  float* pool       = (float*)(w + 64);         // 768 -> 832, pad 896
  int* cursor       = (int*)(w + 896);          // 391*4=1564 -> 2460, pad 2496
  float* dinv       = (float*)(w + 2496);       // 400000 -> 402496
  // (402496..1202496: legacy rowstart/rowend slots, unused)
  int* ents         = (int*)(w + 1202496);      // 391*10240*4 = 16015360 -> 17217856
  uint4* hsA        = (uint4*)(w + 17217856);   // 3.2MB -> 20417856 (bf16x8 x2 per node)
  uint4* hsB        = (uint4*)(w + 20417856);   // 3.2MB -> 23617856
  float2* hs3       = (float2*)(w + 23617856);  // 800000 -> 24417856
  const size_t NEED = 24417856;

  if (ws_size < NEED) {
    k_diag_ws<<<1, 128, 0, stream>>>(d_out, (float)ws_size);
    return;
  }

  // sniff + zero diag/pool/cursor in one dispatch
  k_sniff<<<1, 1024, 0, stream>>>(x, ei, (int*)w);

  // build (bucket scatter; pkt list per bucket, unsorted) + degrees
  k_build<<<NBLKA, 512, 0, stream>>>(ei, diag, cursor, ents);
  k_dinv<<<NBUK, 256, 0, stream>>>(ents, cursor, dinv, diag);

  // layers (bucket-wise fused agg + transform; h bf16-packed, L2-resident)
  k_t0<<<(NT0 + 3) / 4, 256, 0, stream>>>(x, W0, dinv, diag, (unsigned int*)hsA);
  k_aggB<<<NBUK, 256, 0, stream>>>(hsA, ents, cursor, dinv, b0, a0, W1, diag, 1, hsB);
  k_aggB<<<NBUK, 256, 0, stream>>>(hsB, ents, cursor, dinv, b1, a1, W2, diag, 3, hsA);
  k_aggB3<<<NBUK, 256, 0, stream>>>(hsA, ents, cursor, dinv, b2, a2, W3, diag, hs3);
  k_aggB2p<<<NBUK, 256, 0, stream>>>(hs3, ents, cursor, dinv, b3, batch, diag, pool);

  k_final<<<1, 128, 0, stream>>>(pool, diag, d_out);
}

// Round 8
// 271.080 us; speedup vs baseline: 4.5434x; 4.5434x over previous
//
#include <hip/hip_runtime.h>

// GCN: 100K nodes, 3.2M edges, 128 -> 16 -> 16 -> 16 -> 2, mean-pool to 64 graphs.
// R18 = R16 (best, 274.5us) + k_build/k_bsort at 1024 threads (32 waves/CU, was
// 16 -- both are latency-bound LDS-atomic/scan kernels at 2 blocks/CU LDS limit).
// R17 LESSON (k_aggB 344us, occ 13%): bucket-per-block agg kills the grid-level
// parallelism (391 blocks) that hides gather latency -- never trade grid size
// for LDS-atomic accumulation on a latency-bound gather stream.
// Agg inner-loop micro-opts are DEAD ENDS (R11/R14/R15/R16 all neutral; ~1 line
// touch per edge is the invariant floor). Build: R11 bucket scatter + counting
// sort (R13's count->scan->place was 2x worse: write-amp + atomic-return chains).

#define NN 100000
#define NE 3200000
#define NF 128
#define NH 16
#define NO 2
#define NG 64
#define NBLK 391        // ceil(NN/256)
#define BN 256          // nodes per bucket
#define NBUK 391        // ceil(NN/BN)
#define CHUNK 4096
#define NBLKA 782       // ceil(NE/CHUNK)
#define CAPF 10240      // bucket region capacity (mean 8184, sigma ~90)
#define NT0 6250        // 16-node tiles

typedef __attribute__((ext_vector_type(8))) short short8;
typedef __attribute__((ext_vector_type(4))) float float4v;

// ---------------- dtype-dispatched IO helpers ----------------

__device__ __forceinline__ float ldf(const void* p, int i, int f32) {
  if (f32) return ((const float*)p)[i];
  unsigned int u = ((const unsigned short*)p)[i];
  return __uint_as_float(u << 16);
}
__device__ __forceinline__ int ldi(const void* p, int i, int i64) {
  if (i64) return (int)((const long long*)p)[i];
  return ((const int*)p)[i];
}
__device__ __forceinline__ void stf(void* p, int i, float v, int f32) {
  if (f32) {
    ((float*)p)[i] = v;
  } else {
    unsigned int w = __float_as_uint(v);
    unsigned int r = (w + 0x7fffu + ((w >> 16) & 1u)) >> 16;
    ((unsigned short*)p)[i] = (unsigned short)r;
  }
}
__device__ __forceinline__ float bf16lo(unsigned int u) { return __uint_as_float(u << 16); }
__device__ __forceinline__ float bf16hi(unsigned int u) { return __uint_as_float(u & 0xffff0000u); }
__device__ __forceinline__ unsigned int packbf(float x, float y) {
  unsigned int a = __float_as_uint(x);
  a = (a + 0x7fffu + ((a >> 16) & 1u)) >> 16;
  unsigned int b = __float_as_uint(y);
  b = (b + 0x7fffu + ((b >> 16) & 1u)) & 0xffff0000u;
  return a | b;
}
__device__ __forceinline__ short bf16rne(float v) {
  unsigned int w = __float_as_uint(v);
  return (short)((w + 0x7fffu + ((w >> 16) & 1u)) >> 16);
}
__device__ __forceinline__ int okf(float v) { return (v == v) && (fabsf(v) < 1e30f); }
__device__ __forceinline__ void nflag(int* diag, int bad, int bit) {
  if (__any(bad)) {
    if ((threadIdx.x & 63) == 0) atomicOr(diag + 2, 1 << bit);
  }
}
__device__ __forceinline__ int clampi(int v, int hi) {
  return (unsigned)v < (unsigned)hi ? v : 0;
}
__device__ __forceinline__ void add2(float& a0, float& a1, float& a2, float& a3, uint2 v) {
  a0 += bf16lo(v.x);
  a1 += bf16hi(v.x);
  a2 += bf16lo(v.y);
  a3 += bf16hi(v.y);
}

// ---------------- dtype sniff + workspace-control zeroing ----------------

// zbase = first 2496 B of ws: diag(16 ints) | pool(192 fl) | cursor(391+ ints)
__global__ __launch_bounds__(1024) void k_sniff(const void* x, const void* ei, int* zbase) {
  int tid = threadIdx.x;
  if (tid < 624) zbase[tid] = 0;
  __syncthreads();
  if (tid < 64) {
    unsigned int xv = ((const unsigned int*)x)[tid];
    unsigned int e = (xv >> 7) & 0xffu;
    int hit = (e >= 116u && e <= 133u);
    int hits = __popcll(__ballot(hit));
    unsigned int ev = ((const unsigned int*)ei)[2 * tid + 1];
    int nzc = __popcll(__ballot(ev != 0u));
    if (tid == 0) {
      zbase[0] = (hits < 32) ? 1 : 0;  // floats are fp32
      zbase[1] = (nzc == 0) ? 1 : 0;   // ints are int64
    }
  }
}

// ---------------- build: bucketed scatter, one LDS-atomic pass, 1024 threads ----------------

__global__ __launch_bounds__(1024) void k_build(const void* ei, const int* __restrict__ diag,
                                                int* __restrict__ cursor, int* __restrict__ ents) {
  __shared__ int spktA[CHUNK];             // 16K  (dst&255)<<17|src
  __shared__ unsigned short sbid[CHUNK];   // 8K   bucket id
  __shared__ unsigned short srank[CHUNK];  // 8K   rank within bucket
  __shared__ int spktB[CHUNK];             // 16K  reordered pkt
  __shared__ int gpos[CHUNK];              // 16K  global dest
  __shared__ int lscan[1024];              // 4K   counts -> inclusive scan
  __shared__ int sexcl[NBUK];              // 1.6K
  __shared__ int goff[NBUK];               // 1.6K
  int tid = threadIdx.x, blk = blockIdx.x;
  lscan[tid] = 0;
  __syncthreads();
  int i64 = diag[1];
  int base = blk * CHUNK;
  int n = NE - base; n = n > CHUNK ? CHUNK : n;
  for (int i = tid; i < n; i += 1024) {
    int sv = clampi(ldi(ei, base + i, i64), NN);
    int dv = clampi(ldi(ei, NE + base + i, i64), NN);
    int b = dv >> 8;
    spktA[i] = ((dv & 255) << 17) | sv;
    sbid[i] = (unsigned short)b;
    srank[i] = (unsigned short)atomicAdd(&lscan[b], 1);
  }
  __syncthreads();
  // inclusive scan of lscan[0..1023]
  for (int off = 1; off < 1024; off <<= 1) {
    int v = (tid >= off) ? lscan[tid - off] : 0;
    __syncthreads();
    lscan[tid] += v;
    __syncthreads();
  }
  if (tid < NBUK) {
    int b = tid;
    int incl = lscan[b];
    int excl = (b > 0) ? lscan[b - 1] : 0;
    int cnt = incl - excl;
    sexcl[b] = excl;
    int rbase = cnt ? atomicAdd(&cursor[b], cnt) : 0;
    goff[b] = b * CAPF + rbase - excl;
  }
  __syncthreads();
  for (int i = tid; i < n; i += 1024) {
    int b = sbid[i];
    int rr = sexcl[b] + srank[i];
    spktB[rr] = spktA[i];
    int gp = goff[b] + rr;
    int hi = b * CAPF + CAPF - 1;
    gpos[rr] = gp <= hi ? gp : hi;  // overflow clamp (flagged in k_bsort)
  }
  __syncthreads();
  for (int r = tid; r < n; r += 1024) ents[gpos[r]] = spktB[r];
}

// per-bucket counting sort (in-place), one atomic pass, 1024 threads.
__global__ __launch_bounds__(1024) void k_bsort(int* __restrict__ ents, const int* __restrict__ cursor,
                                                int* __restrict__ rowstart, int* __restrict__ rowend,
                                                float* __restrict__ dinv, int* __restrict__ diag) {
  __shared__ int ent[CAPF];               // 40K
  __shared__ unsigned short rnk[CAPF];    // 20K
  __shared__ int lcnt[BN];                // 1K  counts -> inclusive scan
  __shared__ int sexcl[BN];               // 1K
  int tid = threadIdx.x, b = blockIdx.x;
  int bs = b * CAPF;
  int n = cursor[b];
  if (n > CAPF) { n = CAPF; if (tid == 0) atomicOr(diag + 2, 1 << 9); }
  if (tid < BN) lcnt[tid] = 0;
  __syncthreads();
  for (int i = tid; i < n; i += 1024) {
    int e = ents[bs + i];
    ent[i] = e;
    rnk[i] = (unsigned short)atomicAdd(&lcnt[e >> 17], 1);
  }
  __syncthreads();
  int c = (tid < BN) ? lcnt[tid] : 0;
  for (int off = 1; off < BN; off <<= 1) {
    int v = (tid < BN && tid >= off) ? lcnt[tid - off] : 0;
    __syncthreads();
    if (tid < BN) lcnt[tid] += v;
    __syncthreads();
  }
  if (tid < BN) {
    int excl = lcnt[tid] - c;
    sexcl[tid] = excl;
    int node = (b << 8) + tid;
    if (node < NN) {
      rowstart[node] = bs + excl;
      rowend[node] = bs + excl + c;
      dinv[node] = rsqrtf((float)(c + 1));
    }
  }
  __syncthreads();
  for (int i = tid; i < n; i += 1024) {
    int e = ent[i];
    ents[bs + sexcl[e >> 17] + rnk[i]] = e & 0x1FFFF;
  }
}

// ---------------- input transform: hs0 = dinv * (x @ W0), bf16-packed ----------------
// Unified MFMA path; fp32 inputs vector-loaded and RNE-rounded to bf16 in-register.

__global__ __launch_bounds__(256) void k_t0(const void* __restrict__ x, const void* __restrict__ W0,
                                            const float* __restrict__ dinv,
                                            int* __restrict__ diag, unsigned int* __restrict__ out) {
  int tid = threadIdx.x;
  int f32 = diag[0];
  int wave = tid >> 6, lane = tid & 63;
  int nfe = lane & 15, quad = lane >> 4;
  short8 bfr[4];
  if (f32) {
    const float* wf = (const float*)W0;
#pragma unroll
    for (int mf = 0; mf < 4; ++mf) {
      short8 t;
#pragma unroll
      for (int j = 0; j < 8; ++j) t[j] = bf16rne(wf[(mf * 32 + quad * 8 + j) * NH + nfe]);
      bfr[mf] = t;
    }
  } else {
    const unsigned short* wu = (const unsigned short*)W0;
#pragma unroll
    for (int mf = 0; mf < 4; ++mf) {
      short8 t;
#pragma unroll
      for (int j = 0; j < 8; ++j) t[j] = (short)wu[(mf * 32 + quad * 8 + j) * NH + nfe];
      bfr[mf] = t;
    }
  }
  int tile = blockIdx.x * 4 + wave;
  if (tile >= NT0) return;
  int node0 = tile * 16;
  float4v c = {0.f, 0.f, 0.f, 0.f};
  if (f32) {
    const float4v* xrow = (const float4v*)((const float*)x + (node0 + nfe) * NF);
#pragma unroll
    for (int mf = 0; mf < 4; ++mf) {
      float4v f0 = xrow[mf * 8 + quad * 2];
      float4v f1 = xrow[mf * 8 + quad * 2 + 1];
      short8 a;
#pragma unroll
      for (int j = 0; j < 4; ++j) {
        a[j] = bf16rne(f0[j]);
        a[j + 4] = bf16rne(f1[j]);
      }
      c = __builtin_amdgcn_mfma_f32_16x16x32_bf16(a, bfr[mf], c, 0, 0, 0);
    }
  } else {
    const short8* xrow = (const short8*)((const unsigned short*)x + (node0 + nfe) * NF);
#pragma unroll
    for (int mf = 0; mf < 4; ++mf) {
      c = __builtin_amdgcn_mfma_f32_16x16x32_bf16(xrow[mf * 4 + quad], bfr[mf], c, 0, 0, 0);
    }
  }
  int bad = 0;
#pragma unroll
  for (int r = 0; r < 4; ++r) {
    int node = node0 + quad * 4 + r;
    float v = c[r] * dinv[node];
    float o = __shfl_xor(v, 1);
    if (!(nfe & 1)) out[node * 8 + (nfe >> 1)] = packbf(v, o);
    bad |= !okf(v);
  }
  nflag(diag, bad, 0);
}

// ---------------- fused aggregate + PReLU + next transform ----------------

// 4 threads/node, thread p owns features 4p..4p+3 (one uint2 = 8B gather/edge).
// Batch-16: lane p loads int4 of srcs (edges e+4p..e+4p+3, shfl width-4), all 16
// gathers issued into va/vb before consuming.
__global__ __launch_bounds__(256) void k_aggT(const uint2* __restrict__ hin,
                                              const int* __restrict__ srcs,
                                              const int* __restrict__ rowstart,
                                              const int* __restrict__ rowend,
                                              const float* __restrict__ dinv,
                                              const void* __restrict__ b, const void* __restrict__ a,
                                              const void* __restrict__ Wn,
                                              int* __restrict__ diag, int bit,
                                              uint2* __restrict__ hout) {
  __shared__ float ws[NH * NH];
  int tid = threadIdx.x;
  int f32 = diag[0];
  ws[tid] = ldf(Wn, tid, f32);
  __syncthreads();
  int gid = blockIdx.x * 256 + tid;  // NN*4 = 400000
  if (gid >= NN * 4) return;
  int node = gid >> 2, p = gid & 3;
  uint2 self = hin[gid];
  float acc0 = bf16lo(self.x), acc1 = bf16hi(self.x);
  float acc2 = bf16lo(self.y), acc3 = bf16hi(self.y);
  int e = rowstart[node], e1 = rowend[node];
  while ((e & 3) && e < e1) {  // peel to 16B-align srcs for int4 loads
    add2(acc0, acc1, acc2, acc3, hin[srcs[e] * 4 + p]);
    ++e;
  }
  int4 si = make_int4(0, 0, 0, 0);
  if (e + 16 <= e1) si = *(const int4*)(srcs + e + 4 * p);
  while (e + 16 <= e1) {
    int4 sn = si;
    if (e + 32 <= e1) sn = *(const int4*)(srcs + e + 16 + 4 * p);
    uint2 va[8], vb[8];
    va[0] = hin[__shfl(si.x, 0, 4) * 4 + p];
    va[1] = hin[__shfl(si.y, 0, 4) * 4 + p];
    va[2] = hin[__shfl(si.z, 0, 4) * 4 + p];
    va[3] = hin[__shfl(si.w, 0, 4) * 4 + p];
    va[4] = hin[__shfl(si.x, 1, 4) * 4 + p];
    va[5] = hin[__shfl(si.y, 1, 4) * 4 + p];
    va[6] = hin[__shfl(si.z, 1, 4) * 4 + p];
    va[7] = hin[__shfl(si.w, 1, 4) * 4 + p];
    vb[0] = hin[__shfl(si.x, 2, 4) * 4 + p];
    vb[1] = hin[__shfl(si.y, 2, 4) * 4 + p];
    vb[2] = hin[__shfl(si.z, 2, 4) * 4 + p];
    vb[3] = hin[__shfl(si.w, 2, 4) * 4 + p];
    vb[4] = hin[__shfl(si.x, 3, 4) * 4 + p];
    vb[5] = hin[__shfl(si.y, 3, 4) * 4 + p];
    vb[6] = hin[__shfl(si.z, 3, 4) * 4 + p];
    vb[7] = hin[__shfl(si.w, 3, 4) * 4 + p];
#pragma unroll
    for (int k = 0; k < 8; ++k) add2(acc0, acc1, acc2, acc3, va[k]);
#pragma unroll
    for (int k = 0; k < 8; ++k) add2(acc0, acc1, acc2, acc3, vb[k]);
    si = sn;
    e += 16;
  }
  if (e + 8 <= e1) {  // one 8-batch (lane p loads uint2: edges e+2p, e+2p+1)
    uint2 s2 = *(const uint2*)(srcs + e + 2 * p);
    uint2 v[8];
#pragma unroll
    for (int k = 0; k < 4; ++k) {
      int ia = __shfl((int)s2.x, k, 4);
      int ib = __shfl((int)s2.y, k, 4);
      v[2 * k] = hin[ia * 4 + p];
      v[2 * k + 1] = hin[ib * 4 + p];
    }
#pragma unroll
    for (int k = 0; k < 8; ++k) add2(acc0, acc1, acc2, acc3, v[k]);
    e += 8;
  }
  if (e + 4 <= e1) {  // uniform int4 (all lanes same addr, 16B aligned)
    int4 s4 = *(const int4*)(srcs + e);
    uint2 v0 = hin[s4.x * 4 + p];
    uint2 v1 = hin[s4.y * 4 + p];
    uint2 v2 = hin[s4.z * 4 + p];
    uint2 v3 = hin[s4.w * 4 + p];
    add2(acc0, acc1, acc2, acc3, v0);
    add2(acc0, acc1, acc2, acc3, v1);
    add2(acc0, acc1, acc2, acc3, v2);
    add2(acc0, acc1, acc2, acc3, v3);
    e += 4;
  }
  for (; e < e1; ++e) add2(acc0, acc1, acc2, acc3, hin[srcs[e] * 4 + p]);
  float dv = dinv[node];
  float av = ldf(a, 0, f32);
  float p0 = dv * acc0 + ldf(b, 4 * p + 0, f32);
  float p1 = dv * acc1 + ldf(b, 4 * p + 1, f32);
  float p2 = dv * acc2 + ldf(b, 4 * p + 2, f32);
  float p3 = dv * acc3 + ldf(b, 4 * p + 3, f32);
  p0 = p0 > 0.f ? p0 : av * p0;
  p1 = p1 > 0.f ? p1 : av * p1;
  p2 = p2 > 0.f ? p2 : av * p2;
  p3 = p3 > 0.f ? p3 : av * p3;
  float t0 = 0.f, t1 = 0.f, t2 = 0.f, t3 = 0.f;
#pragma unroll
  for (int j = 0; j < 4; ++j) {
    float q0 = __shfl(p0, j, 4);
    float q1 = __shfl(p1, j, 4);
    float q2 = __shfl(p2, j, 4);
    float q3 = __shfl(p3, j, 4);
    const float* w0 = &ws[(4 * j) * NH + 4 * p];
    const float* w1 = &ws[(4 * j + 1) * NH + 4 * p];
    const float* w2 = &ws[(4 * j + 2) * NH + 4 * p];
    const float* w3 = &ws[(4 * j + 3) * NH + 4 * p];
    t0 += q0 * w0[0] + q1 * w1[0] + q2 * w2[0] + q3 * w3[0];
    t1 += q0 * w0[1] + q1 * w1[1] + q2 * w2[1] + q3 * w3[1];
    t2 += q0 * w0[2] + q1 * w1[2] + q2 * w2[2] + q3 * w3[2];
    t3 += q0 * w0[3] + q1 * w1[3] + q2 * w2[3] + q3 * w3[3];
  }
  t0 *= dv; t1 *= dv; t2 *= dv; t3 *= dv;
  uint2 o;
  o.x = packbf(t0, t1);
  o.y = packbf(t2, t3);
  hout[gid] = o;
  nflag(diag, !okf(t0) || !okf(t3), bit);
}

// Last hidden layer: aggregate + PReLU + W3 (16->2), out float2 prescaled by dinv.
__global__ __launch_bounds__(256) void k_aggT3(const uint2* __restrict__ hin,
                                               const int* __restrict__ srcs,
                                               const int* __restrict__ rowstart,
                                               const int* __restrict__ rowend,
                                               const float* __restrict__ dinv,
                                               const void* __restrict__ b, const void* __restrict__ a,
                                               const void* __restrict__ W3,
                                               int* __restrict__ diag, float2* __restrict__ hout) {
  __shared__ float ws[NH * NO];
  int tid = threadIdx.x;
  int f32 = diag[0];
  if (tid < NH * NO) ws[tid] = ldf(W3, tid, f32);
  __syncthreads();
  int gid = blockIdx.x * 256 + tid;
  if (gid >= NN * 4) return;
  int node = gid >> 2, p = gid & 3;
  uint2 self = hin[gid];
  float acc0 = bf16lo(self.x), acc1 = bf16hi(self.x);
  float acc2 = bf16lo(self.y), acc3 = bf16hi(self.y);
  int e = rowstart[node], e1 = rowend[node];
  while ((e & 3) && e < e1) {
    add2(acc0, acc1, acc2, acc3, hin[srcs[e] * 4 + p]);
    ++e;
  }
  int4 si = make_int4(0, 0, 0, 0);
  if (e + 16 <= e1) si = *(const int4*)(srcs + e + 4 * p);
  while (e + 16 <= e1) {
    int4 sn = si;
    if (e + 32 <= e1) sn = *(const int4*)(srcs + e + 16 + 4 * p);
    uint2 va[8], vb[8];
    va[0] = hin[__shfl(si.x, 0, 4) * 4 + p];
    va[1] = hin[__shfl(si.y, 0, 4) * 4 + p];
    va[2] = hin[__shfl(si.z, 0, 4) * 4 + p];
    va[3] = hin[__shfl(si.w, 0, 4) * 4 + p];
    va[4] = hin[__shfl(si.x, 1, 4) * 4 + p];
    va[5] = hin[__shfl(si.y, 1, 4) * 4 + p];
    va[6] = hin[__shfl(si.z, 1, 4) * 4 + p];
    va[7] = hin[__shfl(si.w, 1, 4) * 4 + p];
    vb[0] = hin[__shfl(si.x, 2, 4) * 4 + p];
    vb[1] = hin[__shfl(si.y, 2, 4) * 4 + p];
    vb[2] = hin[__shfl(si.z, 2, 4) * 4 + p];
    vb[3] = hin[__shfl(si.w, 2, 4) * 4 + p];
    vb[4] = hin[__shfl(si.x, 3, 4) * 4 + p];
    vb[5] = hin[__shfl(si.y, 3, 4) * 4 + p];
    vb[6] = hin[__shfl(si.z, 3, 4) * 4 + p];
    vb[7] = hin[__shfl(si.w, 3, 4) * 4 + p];
#pragma unroll
    for (int k = 0; k < 8; ++k) add2(acc0, acc1, acc2, acc3, va[k]);
#pragma unroll
    for (int k = 0; k < 8; ++k) add2(acc0, acc1, acc2, acc3, vb[k]);
    si = sn;
    e += 16;
  }
  if (e + 8 <= e1) {
    uint2 s2 = *(const uint2*)(srcs + e + 2 * p);
    uint2 v[8];
#pragma unroll
    for (int k = 0; k < 4; ++k) {
      int ia = __shfl((int)s2.x, k, 4);
      int ib = __shfl((int)s2.y, k, 4);
      v[2 * k] = hin[ia * 4 + p];
      v[2 * k + 1] = hin[ib * 4 + p];
    }
#pragma unroll
    for (int k = 0; k < 8; ++k) add2(acc0, acc1, acc2, acc3, v[k]);
    e += 8;
  }
  if (e + 4 <= e1) {
    int4 s4 = *(const int4*)(srcs + e);
    uint2 v0 = hin[s4.x * 4 + p];
    uint2 v1 = hin[s4.y * 4 + p];
    uint2 v2 = hin[s4.z * 4 + p];
    uint2 v3 = hin[s4.w * 4 + p];
    add2(acc0, acc1, acc2, acc3, v0);
    add2(acc0, acc1, acc2, acc3, v1);
    add2(acc0, acc1, acc2, acc3, v2);
    add2(acc0, acc1, acc2, acc3, v3);
    e += 4;
  }
  for (; e < e1; ++e) add2(acc0, acc1, acc2, acc3, hin[srcs[e] * 4 + p]);
  float dv = dinv[node];
  float av = ldf(a, 0, f32);
  float p0 = dv * acc0 + ldf(b, 4 * p + 0, f32);
  float p1 = dv * acc1 + ldf(b, 4 * p + 1, f32);
  float p2 = dv * acc2 + ldf(b, 4 * p + 2, f32);
  float p3 = dv * acc3 + ldf(b, 4 * p + 3, f32);
  p0 = p0 > 0.f ? p0 : av * p0;
  p1 = p1 > 0.f ? p1 : av * p1;
  p2 = p2 > 0.f ? p2 : av * p2;
  p3 = p3 > 0.f ? p3 : av * p3;
  float u0 = p0 * ws[(4 * p) * NO]     + p1 * ws[(4 * p + 1) * NO] +
             p2 * ws[(4 * p + 2) * NO] + p3 * ws[(4 * p + 3) * NO];
  float u1 = p0 * ws[(4 * p) * NO + 1]     + p1 * ws[(4 * p + 1) * NO + 1] +
             p2 * ws[(4 * p + 2) * NO + 1] + p3 * ws[(4 * p + 3) * NO + 1];
  u0 += __shfl_xor(u0, 1, 4);
  u0 += __shfl_xor(u0, 2, 4);
  u1 += __shfl_xor(u1, 1, 4);
  u1 += __shfl_xor(u1, 2, 4);
  if (p == 0) hout[node] = make_float2(dv * u0, dv * u1);
  nflag(diag, !okf(u0) || !okf(u1), 6);
}

// Final 2-wide aggregation + b3 + fused mean-pool accumulation. Batch-8 gathers.
__global__ __launch_bounds__(256) void k_agg2p(const float2* __restrict__ tin,
                                               const int* __restrict__ srcs,
                                               const int* __restrict__ rowstart,
                                               const int* __restrict__ rowend,
                                               const float* __restrict__ dinv,
                                               const void* __restrict__ b3,
                                               const void* __restrict__ batch,
                                               int* __restrict__ diag, float* __restrict__ pool) {
  __shared__ float ssum[NG * NO];
  __shared__ float scnt[NG];
  int tid = threadIdx.x;
  int f32 = diag[0], i64 = diag[1];
  if (tid < NG * NO) ssum[tid] = 0.f;
  if (tid < NG) scnt[tid] = 0.f;
  __syncthreads();
  int node = blockIdx.x * 256 + tid;
  if (node < NN) {
    float2 t = tin[node];
    float a0 = t.x, a1 = t.y;
    int e = rowstart[node], e1 = rowend[node];
    while ((e & 3) && e < e1) {  // peel to 16B-align srcs
      float2 hv = tin[srcs[e]];
      a0 += hv.x;
      a1 += hv.y;
      ++e;
    }
    while (e + 8 <= e1) {
      int4 sa = *(const int4*)(srcs + e);
      int4 sb = *(const int4*)(srcs + e + 4);
      float2 h0 = tin[sa.x], h1 = tin[sa.y], h2 = tin[sa.z], h3 = tin[sa.w];
      float2 h4 = tin[sb.x], h5 = tin[sb.y], h6 = tin[sb.z], h7 = tin[sb.w];
      a0 += h0.x + h1.x + h2.x + h3.x;
      a1 += h0.y + h1.y + h2.y + h3.y;
      a0 += h4.x + h5.x + h6.x + h7.x;
      a1 += h4.y + h5.y + h6.y + h7.y;
      e += 8;
    }
    if (e + 4 <= e1) {
      int4 s4 = *(const int4*)(srcs + e);
      float2 h0 = tin[s4.x], h1 = tin[s4.y], h2 = tin[s4.z], h3 = tin[s4.w];
      a0 += h0.x + h1.x + h2.x + h3.x;
      a1 += h0.y + h1.y + h2.y + h3.y;
      e += 4;
    }
    for (; e < e1; ++e) {
      float2 hv = tin[srcs[e]];
      a0 += hv.x;
      a1 += hv.y;
    }
    float dv = dinv[node];
    a0 = dv * a0 + ldf(b3, 0, f32);
    a1 = dv * a1 + ldf(b3, 1, f32);
    int g = ldi(batch, node, i64);
    g = (unsigned)g < NG ? g : 0;
    atomicAdd(&ssum[g * 2], a0);
    atomicAdd(&ssum[g * 2 + 1], a1);
    atomicAdd(&scnt[g], 1.f);
    nflag(diag, !okf(a0) || !okf(a1), 7);
  }
  __syncthreads();
  if (tid < NG * NO && ssum[tid] != 0.f) atomicAdd(&pool[tid], ssum[tid]);
  if (tid < NG && scnt[tid] != 0.f) atomicAdd(&pool[NG * NO + tid], scnt[tid]);
}

__global__ __launch_bounds__(128) void k_final(const float* __restrict__ pool,
                                               const int* __restrict__ diag, void* __restrict__ out) {
  int i = threadIdx.x;
  int f32 = diag[0], i64 = diag[1], stg = diag[2];
  float c = pool[NG * NO + (i >> 1)];
  c = c > 1.f ? c : 1.f;
  float v = pool[i] / c;
  if (stg != 0 || !okf(v)) {
    int stage = stg ? __ffs(stg) : 15;
    v = 1024.0f + stage * 64.0f + f32 * 16.0f + i64 * 8.0f;
  }
  stf(out, i, v, f32);
}

__global__ __launch_bounds__(128) void k_diag_ws(void* out, float v) {
  unsigned int w = __float_as_uint(v);
  ((unsigned short*)out)[threadIdx.x] = (unsigned short)(w >> 16);
}

// ---------------- launch ----------------

extern "C" void kernel_launch(void* const* d_in, const int* in_sizes, int n_in,
                              void* d_out, int out_size, void* d_ws, size_t ws_size,
                              hipStream_t stream) {
  const void* x  = d_in[0];
  const void* ei = d_in[1];
  const void* batch = d_in[2];
  const void* W0 = d_in[3];
  const void* b0 = d_in[4];
  const void* a0 = d_in[5];
  const void* W1 = d_in[6];
  const void* b1 = d_in[7];
  const void* a1 = d_in[8];
  const void* W2 = d_in[9];
  const void* b2 = d_in[10];
  const void* a2 = d_in[11];
  const void* W3 = d_in[12];
  const void* b3 = d_in[13];

  // workspace layout (bytes)
  char* w = (char*)d_ws;
  int* diag         = (int*)(w + 0);            // 64
  float* pool       = (float*)(w + 64);         // 768 -> 832, pad 896
  int* cursor       = (int*)(w + 896);          // 391*4=1564 -> 2460, pad 2496
  float* dinv       = (float*)(w + 2496);       // 400000 -> 402496
  int* rowstart     = (int*)(w + 402496);       // 400000 -> 802496
  int* rowend       = (int*)(w + 802496);       // 400000 -> 1202496
  int* ents         = (int*)(w + 1202496);      // 391*10240*4 = 16015360 -> 17217856
  uint2* hsA        = (uint2*)(w + 17217856);   // 3.2MB -> 20417856 (bf16x2 packed)
  uint2* hsB        = (uint2*)(w + 20417856);   // 3.2MB -> 23617856
  float2* hs3       = (float2*)(w + 23617856);  // 800000 -> 24417856
  const size_t NEED = 24417856;

  if (ws_size < NEED) {
    k_diag_ws<<<1, 128, 0, stream>>>(d_out, (float)ws_size);
    return;
  }

  // sniff + zero diag/pool/cursor in one dispatch
  k_sniff<<<1, 1024, 0, stream>>>(x, ei, (int*)w);

  // build (bucket scatter + per-bucket compaction sort), 1024-thread blocks
  k_build<<<NBLKA, 1024, 0, stream>>>(ei, diag, cursor, ents);
  k_bsort<<<NBUK, 1024, 0, stream>>>(ents, cursor, rowstart, rowend, dinv, diag);

  // layers (fused agg + transform; h bf16-packed, L2-resident)
  k_t0<<<(NT0 + 3) / 4, 256, 0, stream>>>(x, W0, dinv, diag, (unsigned int*)hsA);
  k_aggT<<<(NN * 4 + 255) / 256, 256, 0, stream>>>(hsA, ents, rowstart, rowend, dinv, b0, a0, W1, diag, 1, hsB);
  k_aggT<<<(NN * 4 + 255) / 256, 256, 0, stream>>>(hsB, ents, rowstart, rowend, dinv, b1, a1, W2, diag, 3, hsA);
  k_aggT3<<<(NN * 4 + 255) / 256, 256, 0, stream>>>(hsA, ents, rowstart, rowend, dinv, b2, a2, W3, diag, hs3);
  k_agg2p<<<NBLK, 256, 0, stream>>>(hs3, ents, rowstart, rowend, dinv, b3, batch, diag, pool);

  k_final<<<1, 128, 0, stream>>>(pool, diag, d_out);
}